// Round 10
// baseline (303.111 us; speedup 1.0000x reference)
//
#include <hip/hip_runtime.h>
#include <hip/hip_bf16.h>

#define NB 16
#define NVEC 2048
#define NDIM 32
#define NW 4
#define NHID 128
#define NCLASS 10
#define PITCH 132                 // padded 129 (k and p dims of CT)
#define CTSLOT (PITCH * PITCH)    // 17424 floats per (l,b)
#define MSC 16                    // m-splits for k_C (128 m per block)
#define ZSLOT (129 * 32)

// tanh-approx GELU; validated absmax ~1e-3 vs exact-erf ref (R5-R9).
__device__ __forceinline__ float gelu_fast(float x) {
    float t = 1.5957691216057308f * x * (1.0f + 0.044715f * x * x);
    return x / (1.0f + __expf(-t));
}

// ---------------------------------------------------------------------------
// X = emb[data]; out = bias. 4096 blocks.
__global__ __launch_bounds__(256) void k_embed(const int* __restrict__ data,
                                               const float* __restrict__ emb,
                                               const float* __restrict__ bf,
                                               float* __restrict__ X,
                                               float* __restrict__ out) {
    int gid = blockIdx.x * 256 + threadIdx.x;   // < 1048576
    int row = gid >> 5, d = gid & 31;
    X[gid] = emb[data[row] * NDIM + d];
    if (blockIdx.x == 0 && threadIdx.x < NB * NCLASS)
        out[threadIdx.x] = bf[threadIdx.x % NCLASS];
}

// ---------------------------------------------------------------------------
// Partial C_l[b] = B_l @ A_{l+1}[b] over 128 m's -> CTpart (plain stores).
// R9 analysis: k_C is LDS-instruction-throughput-bound (~254K LDS cyc/CU =
// the measured 106+ us). v3 cuts LDS insts: h-compute 4mm x 4j register
// blocking (w1s reads /4), X read straight from global (L1 broadcast, no
// Xs LDS), Bs in [mm][k] layout so GEMM B-reads are b128 not 8x b32.
// grid (MSC, NB, NW); 256 thr; 8x8 register tile; 2 barriers/s-iter.
__global__ __launch_bounds__(256) void k_C(const float* __restrict__ X,
                                           const float* __restrict__ fw1,
                                           const float* __restrict__ fb1,
                                           const float* __restrict__ fw2,
                                           const float* __restrict__ fb2,
                                           float* __restrict__ CTpart) {
    __shared__ float smem[12544];        // 50.2 KB -> 3 blocks/CU
    float* w1s = smem;                   // 4096:  [d*128 + k]
    float* As  = smem + 4096;           // 32*132: [mm*132 + j]; col 128 = aug
    float* Bs  = smem + 8320;           // 32*132: [mm*132 + k]; col 128 = fb2
    int ms = blockIdx.x, b = blockIdx.y, l = blockIdx.z;
    int tid = threadIdx.x;
    bool hasH = (l < 3);

    const float* fw2l = fw2 + (size_t)l * NHID * NVEC;
    const float* fb2l = fb2 + (size_t)l * NVEC;
    const float* fw1n = fw1 + (size_t)(l + 1) * NDIM * NHID;
    const float* fb1n = fb1 + (size_t)(l + 1) * NHID;

    int hmm = (tid & 7) * 4;             // h-rows mm0..mm0+3
    int jc  = (tid >> 3) * 4;            // h-cols jc..jc+3
    float4 hb = make_float4(0.f, 0.f, 0.f, 0.f);
    if (hasH) {
#pragma unroll
        for (int j = 0; j < 4; ++j)
            ((float4*)w1s)[tid + j * 256] = ((const float4*)fw1n)[tid + j * 256];
        hb = *(const float4*)&fb1n[jc];
    }

    int tk = tid & 15, tj = tid >> 4;
    int kA = tk * 4, kB = kA + 64, j0 = tj * 8;
    float acc[8][8];
#pragma unroll
    for (int jj = 0; jj < 8; ++jj)
#pragma unroll
        for (int kk = 0; kk < 8; ++kk) acc[jj][kk] = 0.f;
    float eR = 0.f, eC = 0.f;

    for (int s = 0; s < 4; ++s) {
        int mbase = ms * 128 + s * 32;
        __syncthreads();                 // prior GEMM readers done (covers w1s t=0)

        {   // stage Bs [mm][k] from global: 4 float4 loads -> 16 scalar stores
#pragma unroll
            for (int j = 0; j < 4; ++j) {
                int i4 = tid + j * 256;
                int k = i4 >> 3, mm4 = (i4 & 7) * 4;
                float4 w = *(const float4*)&fw2l[(size_t)k * NVEC + mbase + mm4];
                Bs[(mm4 + 0) * 132 + k] = w.x;
                Bs[(mm4 + 1) * 132 + k] = w.y;
                Bs[(mm4 + 2) * 132 + k] = w.z;
                Bs[(mm4 + 3) * 132 + k] = w.w;
            }
            if (tid < 32) Bs[tid * 132 + 128] = fb2l[mbase + tid];
        }

        {   // build As [mm][j]: h from global X + LDS w1s (l<3) or X pad (l=3)
            const float* Xrow = X + ((size_t)b * NVEC + mbase + hmm) * NDIM;
            if (hasH) {
                float ha[4][4];
#pragma unroll
                for (int u = 0; u < 4; ++u) {
                    ha[u][0] = hb.x; ha[u][1] = hb.y;
                    ha[u][2] = hb.z; ha[u][3] = hb.w;
                }
#pragma unroll
                for (int dc = 0; dc < 4; ++dc) {
                    float xv[4][8];
#pragma unroll
                    for (int u = 0; u < 4; ++u) {
                        float4 x0 = *(const float4*)&Xrow[u * NDIM + dc * 8];
                        float4 x1 = *(const float4*)&Xrow[u * NDIM + dc * 8 + 4];
                        xv[u][0] = x0.x; xv[u][1] = x0.y; xv[u][2] = x0.z; xv[u][3] = x0.w;
                        xv[u][4] = x1.x; xv[u][5] = x1.y; xv[u][6] = x1.z; xv[u][7] = x1.w;
                    }
#pragma unroll
                    for (int dd = 0; dd < 8; ++dd) {
                        float4 w = *(const float4*)&w1s[(dc * 8 + dd) * NHID + jc];
#pragma unroll
                        for (int u = 0; u < 4; ++u) {
                            ha[u][0] += xv[u][dd] * w.x;
                            ha[u][1] += xv[u][dd] * w.y;
                            ha[u][2] += xv[u][dd] * w.z;
                            ha[u][3] += xv[u][dd] * w.w;
                        }
                    }
                }
#pragma unroll
                for (int u = 0; u < 4; ++u) {
                    float4 g;
                    g.x = gelu_fast(ha[u][0]); g.y = gelu_fast(ha[u][1]);
                    g.z = gelu_fast(ha[u][2]); g.w = gelu_fast(ha[u][3]);
                    *(float4*)&As[(hmm + u) * 132 + jc] = g;
                }
            } else {
#pragma unroll
                for (int u = 0; u < 4; ++u) {
                    float4 g = make_float4(0.f, 0.f, 0.f, 0.f);
                    if (jc < NDIM) g = *(const float4*)&Xrow[u * NDIM + jc];
                    *(float4*)&As[(hmm + u) * 132 + jc] = g;
                }
            }
            if (tid < 32) As[tid * 132 + 128] = hasH ? 1.f : 0.f;  // aug column
        }
        __syncthreads();                 // As/Bs ready

        // main gemm: C[k][j] += B[mm][k]*A[mm][j]; 4 b128 per mm per thread
#pragma unroll 4
        for (int mm = 0; mm < 32; ++mm) {
            float4 a0 = *(const float4*)&As[mm * 132 + j0];       // 4-addr bcast
            float4 a1 = *(const float4*)&As[mm * 132 + j0 + 4];
            float4 b0 = *(const float4*)&Bs[mm * 132 + kA];       // full-BW
            float4 b1 = *(const float4*)&Bs[mm * 132 + kB];
            float av[8] = {a0.x, a0.y, a0.z, a0.w, a1.x, a1.y, a1.z, a1.w};
            float bv[8] = {b0.x, b0.y, b0.z, b0.w, b1.x, b1.y, b1.z, b1.w};
#pragma unroll
            for (int jj = 0; jj < 8; ++jj)
#pragma unroll
                for (int kk = 0; kk < 8; ++kk) acc[jj][kk] += av[jj] * bv[kk];
        }
        // edges: C row k=128 (B=fb2) over j<129; col j=128 over k<128
        if (tid < 129) {
#pragma unroll 8
            for (int mm = 0; mm < 32; ++mm)
                eR += Bs[mm * 132 + 128] * As[mm * 132 + tid];
        }
        if (tid >= 124 && tid < 252) {
            int ke = tid - 124;
#pragma unroll 8
            for (int mm = 0; mm < 32; ++mm)
                eC += Bs[mm * 132 + ke] * As[mm * 132 + 128];
        }
    }

    float* ct = CTpart + ((size_t)ms * NW * NB + (size_t)l * NB + b) * CTSLOT;
#pragma unroll
    for (int jj = 0; jj < 8; ++jj) {
        *(float4*)&ct[(j0 + jj) * PITCH + kA] =
            make_float4(acc[jj][0], acc[jj][1], acc[jj][2], acc[jj][3]);
        *(float4*)&ct[(j0 + jj) * PITCH + kB] =
            make_float4(acc[jj][4], acc[jj][5], acc[jj][6], acc[jj][7]);
    }
    if (tid < 129) ct[tid * PITCH + 128] = eR;
    if (tid >= 124 && tid < 252) ct[128 * PITCH + (tid - 124)] = eC;
}

// ---------------------------------------------------------------------------
// CT[slot][p][k] = sum_ms CTpart[ms][slot][p][k] (k<129), 0 for pads.
// Domain: 64 slots x 129 p x 132 k = 1,089,792 = 4257 * 256.
__global__ __launch_bounds__(256) void k_Cred(const float* __restrict__ CTpart,
                                              float* __restrict__ CT) {
    int gid = blockIdx.x * 256 + threadIdx.x;
    int slot = gid / (129 * PITCH);
    int r = gid - slot * (129 * PITCH);
    int p = r / PITCH, k = r - p * PITCH;
    float s = 0.f;
    if (k < 129) {
        const float* base = CTpart + (size_t)slot * CTSLOT + p * PITCH + k;
#pragma unroll
        for (int ms = 0; ms < MSC; ++ms)
            s += base[(size_t)ms * (NW * NB) * CTSLOT];
    }
    CT[(size_t)slot * CTSLOT + p * PITCH + k] = s;
}

// ---------------------------------------------------------------------------
// Z = C_0 @ C_1 @ C_2 @ T per b, chained right-to-left in LDS.
// grid (4 jg, NB), 192 thr.
__global__ __launch_bounds__(192) void k_Z(const float* __restrict__ CT,
                                           float* __restrict__ Zbuf) {
    __shared__ float Zp[2][PITCH * 8];
    int jg = blockIdx.x, b = blockIdx.y;
    int t = threadIdx.x;
    int j0 = jg * 8;

    const float* ct3 = CT + (size_t)(3 * NB + b) * CTSLOT;
    if (t < PITCH) {
#pragma unroll
        for (int jj = 0; jj < 8; ++jj)
            Zp[0][t * 8 + jj] = ct3[(j0 + jj) * PITCH + t];
    }
    __syncthreads();

    int cur = 0;
    for (int l = 2; l >= 0; --l) {
        const float* ctl = CT + (size_t)(l * NB + b) * CTSLOT;
        float acc[8] = {0.f, 0.f, 0.f, 0.f, 0.f, 0.f, 0.f, 0.f};
        if (t < PITCH) {
#pragma unroll 4
            for (int p = 0; p < 129; ++p) {
                float cv = ctl[p * PITCH + t];
                float4 z0 = *(const float4*)&Zp[cur][p * 8];
                float4 z1 = *(const float4*)&Zp[cur][p * 8 + 4];
                acc[0] += cv * z0.x; acc[1] += cv * z0.y;
                acc[2] += cv * z0.z; acc[3] += cv * z0.w;
                acc[4] += cv * z1.x; acc[5] += cv * z1.y;
                acc[6] += cv * z1.z; acc[7] += cv * z1.w;
            }
        }
        __syncthreads();
        if (t < PITCH) {
            *(float4*)&Zp[1 - cur][t * 8] = make_float4(acc[0], acc[1], acc[2], acc[3]);
            *(float4*)&Zp[1 - cur][t * 8 + 4] = make_float4(acc[4], acc[5], acc[6], acc[7]);
        }
        __syncthreads();
        cur ^= 1;
    }
    if (t < 129) {
        *(float4*)&Zbuf[(size_t)b * ZSLOT + t * 32 + j0] =
            make_float4(Zp[cur][t * 8], Zp[cur][t * 8 + 1], Zp[cur][t * 8 + 2], Zp[cur][t * 8 + 3]);
        *(float4*)&Zbuf[(size_t)b * ZSLOT + t * 32 + j0 + 4] =
            make_float4(Zp[cur][t * 8 + 4], Zp[cur][t * 8 + 5], Zp[cur][t * 8 + 6], Zp[cur][t * 8 + 7]);
    }
}

// ---------------------------------------------------------------------------
// out[b,c] += sum_n,d (h_0[n,:]@Z[0:128,:] + Z[128,:])[d] * Wf[n*32+d, c]
// grid (16 nc, NB); 256 thr; 128 n-rows per block in 4 subtiles of 32.
__global__ __launch_bounds__(256, 2) void k_out(const float* __restrict__ X,
                                                const float* __restrict__ fw1,
                                                const float* __restrict__ fb1,
                                                const float* __restrict__ Zbuf,
                                                const float* __restrict__ Wf,
                                                float* __restrict__ out) {
    __shared__ float w1s[NDIM * NHID];
    __shared__ float Zs[PITCH * 36];
    __shared__ float Xs[32 * 36];
    __shared__ float hs[32 * 133];
    __shared__ float vs[32 * 33];
    __shared__ float red[4][NCLASS];
    int nc = blockIdx.x, b = blockIdx.y;
    int tid = threadIdx.x;

#pragma unroll
    for (int j = 0; j < 4; ++j)
        ((float4*)w1s)[tid + j * 256] = ((const float4*)fw1)[tid + j * 256];
    for (int i = tid; i < ZSLOT; i += 256) {
        int k = i >> 5, d = i & 31;
        Zs[k * 36 + d] = Zbuf[(size_t)b * ZSLOT + i];
    }
    int hm = tid >> 3, jbi = tid & 7;
    float4 hb[4];
#pragma unroll
    for (int t = 0; t < 4; ++t) hb[t] = *(const float4*)&fb1[32 * t + 4 * jbi];

    float acc[NCLASS];
#pragma unroll
    for (int c = 0; c < NCLASS; ++c) acc[c] = 0.f;

    for (int ss = 0; ss < 4; ++ss) {
        int n0 = nc * 128 + ss * 32;
        __syncthreads();
        {
            float4 v = ((const float4*)(X + ((size_t)b * NVEC + n0) * NDIM))[tid];
            int mm = tid >> 3, d4 = (tid & 7) * 4;
            Xs[mm * 36 + d4] = v.x; Xs[mm * 36 + d4 + 1] = v.y;
            Xs[mm * 36 + d4 + 2] = v.z; Xs[mm * 36 + d4 + 3] = v.w;
        }
        __syncthreads();
        {   // h_0 tile: 1 mm x {32t+4*jbi} j-set
            float ha[16];
#pragma unroll
            for (int t = 0; t < 4; ++t) {
                ha[4 * t] = hb[t].x; ha[4 * t + 1] = hb[t].y;
                ha[4 * t + 2] = hb[t].z; ha[4 * t + 3] = hb[t].w;
            }
#pragma unroll 8
            for (int d = 0; d < NDIM; ++d) {
                float x = Xs[hm * 36 + d];
#pragma unroll
                for (int t = 0; t < 4; ++t) {
                    float4 w = *(const float4*)&w1s[d * NHID + 32 * t + 4 * jbi];
                    ha[4 * t] += x * w.x; ha[4 * t + 1] += x * w.y;
                    ha[4 * t + 2] += x * w.z; ha[4 * t + 3] += x * w.w;
                }
            }
#pragma unroll
            for (int t = 0; t < 4; ++t) {
                int jb = 32 * t + 4 * jbi;
                hs[hm * 133 + jb] = gelu_fast(ha[4 * t]);
                hs[hm * 133 + jb + 1] = gelu_fast(ha[4 * t + 1]);
                hs[hm * 133 + jb + 2] = gelu_fast(ha[4 * t + 2]);
                hs[hm * 133 + jb + 3] = gelu_fast(ha[4 * t + 3]);
            }
        }
        __syncthreads();
        {   // V tile
            int r = tid & 31, d0 = (tid >> 5) * 4;
            float4 a = *(const float4*)&Zs[128 * 36 + d0];
#pragma unroll 8
            for (int k = 0; k < NHID; ++k) {
                float h = hs[r * 133 + k];
                float4 z = *(const float4*)&Zs[k * 36 + d0];
                a.x += h * z.x; a.y += h * z.y; a.z += h * z.z; a.w += h * z.w;
            }
            vs[r * 33 + d0] = a.x; vs[r * 33 + d0 + 1] = a.y;
            vs[r * 33 + d0 + 2] = a.z; vs[r * 33 + d0 + 3] = a.w;
        }
        __syncthreads();
        {   // Wf projection
#pragma unroll
            for (int i = 0; i < 4; ++i) {
                int q = tid + i * 256;
                int r = q >> 5, d = q & 31;
                float v = vs[r * 33 + d];
                const float* wr = Wf + ((size_t)(n0 + r) * NDIM + d) * NCLASS;
#pragma unroll
                for (int c = 0; c < NCLASS; ++c) acc[c] += v * wr[c];
            }
        }
    }

#pragma unroll
    for (int off = 32; off >= 1; off >>= 1)
#pragma unroll
        for (int c = 0; c < NCLASS; ++c) acc[c] += __shfl_down(acc[c], off);
    if ((tid & 63) == 0) {
#pragma unroll
        for (int c = 0; c < NCLASS; ++c) red[tid >> 6][c] = acc[c];
    }
    __syncthreads();
    if (tid < NCLASS)
        atomicAdd(&out[b * NCLASS + tid],
                  red[0][tid] + red[1][tid] + red[2][tid] + red[3][tid]);
}

// ---------------------------------------------------------------------------
extern "C" void kernel_launch(void* const* d_in, const int* in_sizes, int n_in,
                              void* d_out, int out_size, void* d_ws, size_t ws_size,
                              hipStream_t stream) {
    const int*   data = (const int*)d_in[0];
    const float* emb  = (const float*)d_in[1];
    const float* fw1  = (const float*)d_in[2];
    const float* fb1  = (const float*)d_in[3];
    const float* fw2  = (const float*)d_in[4];
    const float* fb2  = (const float*)d_in[5];
    const float* Wf   = (const float*)d_in[6];
    const float* bf   = (const float*)d_in[7];
    float* out = (float*)d_out;

    float* X      = (float*)d_ws;                         // 1,048,576 f
    float* CTpart = X + NB * NVEC * NDIM;                 // 16*64*17424 f (71 MB)
    float* CT     = CTpart + (size_t)MSC * NW * NB * CTSLOT;
    float* Zbuf   = CT + (size_t)NW * NB * CTSLOT;        // total ~80.3 MB (<= R3's 83.7 proven)

    k_embed<<<dim3((NB * NVEC * NDIM) / 256), 256, 0, stream>>>(data, emb, bf, X, out);
    k_C<<<dim3(MSC, NB, NW), 256, 0, stream>>>(X, fw1, fb1, fw2, fb2, CTpart);
    k_Cred<<<dim3(4257), 256, 0, stream>>>(CTpart, CT);
    k_Z<<<dim3(4, NB), 192, 0, stream>>>(CT, Zbuf);
    k_out<<<dim3(16, NB), 256, 0, stream>>>(X, fw1, fb1, Zbuf, Wf, out);
}

// Round 11
// 267.465 us; speedup vs baseline: 1.1333x; 1.1333x over previous
//
#include <hip/hip_runtime.h>
#include <hip/hip_bf16.h>

#define NB 16
#define NVEC 2048
#define NDIM 32
#define NW 4
#define NHID 128
#define NCLASS 10
#define PITCH 132                 // padded 129 (k and p dims of CT)
#define CTSLOT (PITCH * PITCH)    // 17424 floats per (l,b)
#define MSC 8                     // m-splits for k_C (256 m per block)
#define ZSLOT (129 * 32)
#define HP 40                     // LDS bf16 row pitch (80 B: 16B-aligned frags)

typedef __attribute__((ext_vector_type(8))) short bf16x8;   // MFMA A/B frag
typedef __attribute__((ext_vector_type(4))) float f32x4;    // MFMA C/D frag
typedef __attribute__((ext_vector_type(4))) short short4v;

// tanh-approx GELU; validated absmax ~1e-3 vs exact-erf ref (R5-R10).
__device__ __forceinline__ float gelu_fast(float x) {
    float t = 1.5957691216057308f * x * (1.0f + 0.044715f * x * x);
    return x / (1.0f + __expf(-t));
}
// fp32 -> bf16 (RNE)
__device__ __forceinline__ short f2bf(float x) {
    union { float f; unsigned u; } v; v.f = x;
    unsigned r = v.u + 0x7FFF + ((v.u >> 16) & 1);
    return (short)(r >> 16);
}

// ---------------------------------------------------------------------------
// X = emb[data]; out = bias. 4096 blocks.
__global__ __launch_bounds__(256) void k_embed(const int* __restrict__ data,
                                               const float* __restrict__ emb,
                                               const float* __restrict__ bf,
                                               float* __restrict__ X,
                                               float* __restrict__ out) {
    int gid = blockIdx.x * 256 + threadIdx.x;   // < 1048576
    int row = gid >> 5, d = gid & 31;
    X[gid] = emb[data[row] * NDIM + d];
    if (blockIdx.x == 0 && threadIdx.x < NB * NCLASS)
        out[threadIdx.x] = bf[threadIdx.x % NCLASS];
}

// ---------------------------------------------------------------------------
// MFMA k_C: partial C_l[b] = [fw2_l; fb2_l^T] @ [h_{l+1} | 1] over 256 m's.
// fp32 floor for this kernel is ~35 us (R8 measured 115); bf16 MFMA floor ~5.
// h computed via mfma(X, fw1) too; edges folded in by padding k,j to 144
// (fw2b row 128 = fb2, rows 129+ = 0; hT row 128 = aug 1.0, rows 129+ = 0).
// Layouts per m89/m120: A[m=lane&15][k=quad*8+i], B[k=quad*8+i][n=lane&15],
// D[row=quad*4+reg][col=lane&15]. grid (MSC, NB, NW), 256 thr = 4 waves.
__global__ __launch_bounds__(256) void k_C(const float* __restrict__ X,
                                           const float* __restrict__ fw1,
                                           const float* __restrict__ fb1,
                                           const float* __restrict__ fw2,
                                           const float* __restrict__ fb2,
                                           float* __restrict__ CTpart) {
    __shared__ short w1T[128 * HP];      // [j][d] bf16 (l<3)
    __shared__ short Xb[32 * HP];        // [m][d] bf16 (l<3)
    __shared__ short fw2b[144 * HP];     // [k][m] bf16; row 128 = fb2
    __shared__ short hT[144 * HP];       // [j][m] bf16; row 128 = aug
    int ms = blockIdx.x, b = blockIdx.y, l = blockIdx.z;
    int tid = threadIdx.x;
    int wv = tid >> 6, lane = tid & 63, quad = lane >> 4, l16 = lane & 15;
    bool hasH = (l < 3);

    const float* fw2l = fw2 + (size_t)l * NHID * NVEC;
    const float* fb2l = fb2 + (size_t)l * NVEC;

    // one-time pad/zero init + w1T staging
    for (int i = tid; i < 15 * HP; i += 256) fw2b[129 * HP + i] = 0;
    if (hasH) {
        for (int i = tid; i < 15 * HP; i += 256) hT[129 * HP + i] = 0;
        if (tid < HP) hT[128 * HP + tid] = 0x3F80;   // aug row = bf16 1.0
        const float* fw1n = fw1 + (size_t)(l + 1) * NDIM * NHID;
        for (int i4 = tid; i4 < 1024; i4 += 256) {   // transpose fw1 -> w1T[j][d]
            int d = i4 >> 5, j4 = (i4 & 31) * 4;
            float4 w = *(const float4*)&fw1n[d * NHID + j4];
            w1T[(j4 + 0) * HP + d] = f2bf(w.x);
            w1T[(j4 + 1) * HP + d] = f2bf(w.y);
            w1T[(j4 + 2) * HP + d] = f2bf(w.z);
            w1T[(j4 + 3) * HP + d] = f2bf(w.w);
        }
    } else {
        for (int i = tid; i < 112 * HP; i += 256) hT[32 * HP + i] = 0;
    }
    __syncthreads();

    // loop-invariant h-MFMA B-frags (fw1) + biases
    bf16x8 w1B[2]; float hbias[2];
    if (hasH) {
        const float* fb1n = fb1 + (size_t)(l + 1) * NHID;
#pragma unroll
        for (int t = 0; t < 2; ++t) {
            int j = wv * 32 + t * 16 + l16;
            w1B[t] = *(bf16x8*)&w1T[j * HP + quad * 8];
            hbias[t] = fb1n[j];
        }
    }

    int JS = hasH ? 9 : 2;               // j-tiles (j padded to 144; l=3: j<32)
    int jsA = hasH ? 2 * wv : wv;        // strip-8 (k=128 row) tile ownership
    int jsB = hasH ? 2 * wv + 1 : -1;
    f32x4 accM[2][9]; f32x4 acc8[3];
    f32x4 z4 = {0.f, 0.f, 0.f, 0.f};
#pragma unroll
    for (int t = 0; t < 2; ++t)
#pragma unroll
        for (int js = 0; js < 9; ++js) accM[t][js] = z4;
    acc8[0] = z4; acc8[1] = z4; acc8[2] = z4;

    for (int s = 0; s < 8; ++s) {
        int mbase = ms * 256 + s * 32;
        __syncthreads();                 // prior chunk's frag reads done

        // stage fw2b[k][m] rows 0..127 + row 128 = fb2
#pragma unroll
        for (int jj = 0; jj < 4; ++jj) {
            int i4 = tid + jj * 256;
            int k = i4 >> 3, m4 = (i4 & 7) * 4;
            float4 w = *(const float4*)&fw2l[(size_t)k * NVEC + mbase + m4];
            short4v p; p[0] = f2bf(w.x); p[1] = f2bf(w.y);
            p[2] = f2bf(w.z); p[3] = f2bf(w.w);
            *(short4v*)&fw2b[k * HP + m4] = p;
        }
        if (tid < 32) fw2b[128 * HP + tid] = f2bf(fb2l[mbase + tid]);

        if (hasH) {
            {   // stage Xb[m][d]
                int m = tid >> 3, d4 = (tid & 7) * 4;
                float4 xv = *(const float4*)&X[((size_t)b * NVEC + mbase + m) * NDIM + d4];
                short4v p; p[0] = f2bf(xv.x); p[1] = f2bf(xv.y);
                p[2] = f2bf(xv.z); p[3] = f2bf(xv.w);
                *(short4v*)&Xb[m * HP + d4] = p;
            }
            __syncthreads();             // Xb ready
            // h = gelu(X@fw1 + fb1) via mfma; store transposed hT[j][m]
#pragma unroll
            for (int mt = 0; mt < 2; ++mt) {
                bf16x8 xa = *(bf16x8*)&Xb[(mt * 16 + l16) * HP + quad * 8];
#pragma unroll
                for (int t = 0; t < 2; ++t) {
                    f32x4 ha = __builtin_amdgcn_mfma_f32_16x16x32_bf16(xa, w1B[t], z4, 0, 0, 0);
                    int j = wv * 32 + t * 16 + l16;
                    short4v hp;
                    hp[0] = f2bf(gelu_fast(ha[0] + hbias[t]));
                    hp[1] = f2bf(gelu_fast(ha[1] + hbias[t]));
                    hp[2] = f2bf(gelu_fast(ha[2] + hbias[t]));
                    hp[3] = f2bf(gelu_fast(ha[3] + hbias[t]));
                    *(short4v*)&hT[j * HP + mt * 16 + quad * 4] = hp;
                }
            }
        } else {
            // l=3: hT rows 0..31 = X^T (aug/pad rows stay 0)
            int m = tid >> 3, j4 = (tid & 7) * 4;
            float4 xv = *(const float4*)&X[((size_t)b * NVEC + mbase + m) * NDIM + j4];
            hT[(j4 + 0) * HP + m] = f2bf(xv.x);
            hT[(j4 + 1) * HP + m] = f2bf(xv.y);
            hT[(j4 + 2) * HP + m] = f2bf(xv.z);
            hT[(j4 + 3) * HP + m] = f2bf(xv.w);
        }
        __syncthreads();                 // hT + fw2b ready

        // main MFMA: wave wv owns k-strips {2wv, 2wv+1} + part of strip 8
        bf16x8 aM0 = *(bf16x8*)&fw2b[(wv * 32 + l16) * HP + quad * 8];
        bf16x8 aM1 = *(bf16x8*)&fw2b[(wv * 32 + 16 + l16) * HP + quad * 8];
        bf16x8 a8  = *(bf16x8*)&fw2b[(128 + l16) * HP + quad * 8];
#pragma unroll
        for (int js = 0; js < 9; ++js) {
            if (js >= JS) break;
            bf16x8 bF = *(bf16x8*)&hT[(js * 16 + l16) * HP + quad * 8];
            accM[0][js] = __builtin_amdgcn_mfma_f32_16x16x32_bf16(aM0, bF, accM[0][js], 0, 0, 0);
            accM[1][js] = __builtin_amdgcn_mfma_f32_16x16x32_bf16(aM1, bF, accM[1][js], 0, 0, 0);
            if (js == jsA)
                acc8[0] = __builtin_amdgcn_mfma_f32_16x16x32_bf16(a8, bF, acc8[0], 0, 0, 0);
            else if (js == jsB)
                acc8[1] = __builtin_amdgcn_mfma_f32_16x16x32_bf16(a8, bF, acc8[1], 0, 0, 0);
            else if (hasH && wv == 3 && js == 8)
                acc8[2] = __builtin_amdgcn_mfma_f32_16x16x32_bf16(a8, bF, acc8[2], 0, 0, 0);
        }
    }

    // store: CT layout ct[j][k] = C[k][j]; D row=k_local=quad*4+reg -> float4
    float* ct = CTpart + ((size_t)ms * (NW * NB) + (size_t)l * NB + b) * CTSLOT;
#pragma unroll
    for (int t = 0; t < 2; ++t)
#pragma unroll
        for (int js = 0; js < 9; ++js) {
            if (js >= JS) break;
            int j = js * 16 + l16;
            if (j <= 128) {
                int k0 = wv * 32 + t * 16 + quad * 4;
                *(f32x4*)&ct[(size_t)j * PITCH + k0] = accM[t][js];
            }
        }
    if (quad == 0) {                     // strip 8: k = 128 (+pads 129..131)
        if (jsA < JS) {
            int j = jsA * 16 + l16;
            if (j <= 128) *(f32x4*)&ct[(size_t)j * PITCH + 128] = acc8[0];
        }
        if (jsB >= 0) {
            int j = jsB * 16 + l16;
            if (j <= 128) *(f32x4*)&ct[(size_t)j * PITCH + 128] = acc8[1];
        }
        if (hasH && wv == 3) {
            int j = 128 + l16;
            if (j <= 128) *(f32x4*)&ct[(size_t)j * PITCH + 128] = acc8[2];
        }
    }
}

// ---------------------------------------------------------------------------
// CT[slot][p][k] = sum_ms CTpart[ms][slot][p][k] (k<129), 0 for pads.
// Domain: 64 slots x 129 p x 132 k = 1,089,792 = 4257 * 256.
__global__ __launch_bounds__(256) void k_Cred(const float* __restrict__ CTpart,
                                              float* __restrict__ CT) {
    int gid = blockIdx.x * 256 + threadIdx.x;
    int slot = gid / (129 * PITCH);
    int r = gid - slot * (129 * PITCH);
    int p = r / PITCH, k = r - p * PITCH;
    float s = 0.f;
    if (k < 129) {
        const float* base = CTpart + (size_t)slot * CTSLOT + p * PITCH + k;
#pragma unroll
        for (int ms = 0; ms < MSC; ++ms)
            s += base[(size_t)ms * (NW * NB) * CTSLOT];
    }
    CT[(size_t)slot * CTSLOT + p * PITCH + k] = s;
}

// ---------------------------------------------------------------------------
// Z = C_0 @ C_1 @ C_2 @ T per b, chained right-to-left in LDS.
// grid (4 jg, NB), 192 thr.
__global__ __launch_bounds__(192) void k_Z(const float* __restrict__ CT,
                                           float* __restrict__ Zbuf) {
    __shared__ float Zp[2][PITCH * 8];
    int jg = blockIdx.x, b = blockIdx.y;
    int t = threadIdx.x;
    int j0 = jg * 8;

    const float* ct3 = CT + (size_t)(3 * NB + b) * CTSLOT;
    if (t < PITCH) {
#pragma unroll
        for (int jj = 0; jj < 8; ++jj)
            Zp[0][t * 8 + jj] = ct3[(j0 + jj) * PITCH + t];
    }
    __syncthreads();

    int cur = 0;
    for (int l = 2; l >= 0; --l) {
        const float* ctl = CT + (size_t)(l * NB + b) * CTSLOT;
        float acc[8] = {0.f, 0.f, 0.f, 0.f, 0.f, 0.f, 0.f, 0.f};
        if (t < PITCH) {
#pragma unroll 4
            for (int p = 0; p < 129; ++p) {
                float cv = ctl[p * PITCH + t];
                float4 z0 = *(const float4*)&Zp[cur][p * 8];
                float4 z1 = *(const float4*)&Zp[cur][p * 8 + 4];
                acc[0] += cv * z0.x; acc[1] += cv * z0.y;
                acc[2] += cv * z0.z; acc[3] += cv * z0.w;
                acc[4] += cv * z1.x; acc[5] += cv * z1.y;
                acc[6] += cv * z1.z; acc[7] += cv * z1.w;
            }
        }
        __syncthreads();
        if (t < PITCH) {
            *(float4*)&Zp[1 - cur][t * 8] = make_float4(acc[0], acc[1], acc[2], acc[3]);
            *(float4*)&Zp[1 - cur][t * 8 + 4] = make_float4(acc[4], acc[5], acc[6], acc[7]);
        }
        __syncthreads();
        cur ^= 1;
    }
    if (t < 129) {
        *(float4*)&Zbuf[(size_t)b * ZSLOT + t * 32 + j0] =
            make_float4(Zp[cur][t * 8], Zp[cur][t * 8 + 1], Zp[cur][t * 8 + 2], Zp[cur][t * 8 + 3]);
        *(float4*)&Zbuf[(size_t)b * ZSLOT + t * 32 + j0 + 4] =
            make_float4(Zp[cur][t * 8 + 4], Zp[cur][t * 8 + 5], Zp[cur][t * 8 + 6], Zp[cur][t * 8 + 7]);
    }
}

// ---------------------------------------------------------------------------
// out[b,c] += sum_n,d (h_0[n,:]@Z[0:128,:] + Z[128,:])[d] * Wf[n*32+d, c]
// grid (16 nc, NB); 256 thr; 128 n-rows per block in 4 subtiles of 32.
__global__ __launch_bounds__(256, 2) void k_out(const float* __restrict__ X,
                                                const float* __restrict__ fw1,
                                                const float* __restrict__ fb1,
                                                const float* __restrict__ Zbuf,
                                                const float* __restrict__ Wf,
                                                float* __restrict__ out) {
    __shared__ float w1s[NDIM * NHID];
    __shared__ float Zs[PITCH * 36];
    __shared__ float Xs[32 * 36];
    __shared__ float hs[32 * 133];
    __shared__ float vs[32 * 33];
    __shared__ float red[4][NCLASS];
    int nc = blockIdx.x, b = blockIdx.y;
    int tid = threadIdx.x;

#pragma unroll
    for (int j = 0; j < 4; ++j)
        ((float4*)w1s)[tid + j * 256] = ((const float4*)fw1)[tid + j * 256];
    for (int i = tid; i < ZSLOT; i += 256) {
        int k = i >> 5, d = i & 31;
        Zs[k * 36 + d] = Zbuf[(size_t)b * ZSLOT + i];
    }
    int hm = tid >> 3, jbi = tid & 7;
    float4 hb[4];
#pragma unroll
    for (int t = 0; t < 4; ++t) hb[t] = *(const float4*)&fb1[32 * t + 4 * jbi];

    float acc[NCLASS];
#pragma unroll
    for (int c = 0; c < NCLASS; ++c) acc[c] = 0.f;

    for (int ss = 0; ss < 4; ++ss) {
        int n0 = nc * 128 + ss * 32;
        __syncthreads();
        {
            float4 v = ((const float4*)(X + ((size_t)b * NVEC + n0) * NDIM))[tid];
            int mm = tid >> 3, d4 = (tid & 7) * 4;
            Xs[mm * 36 + d4] = v.x; Xs[mm * 36 + d4 + 1] = v.y;
            Xs[mm * 36 + d4 + 2] = v.z; Xs[mm * 36 + d4 + 3] = v.w;
        }
        __syncthreads();
        {   // h_0 tile: 1 mm x {32t+4*jbi} j-set
            float ha[16];
#pragma unroll
            for (int t = 0; t < 4; ++t) {
                ha[4 * t] = hb[t].x; ha[4 * t + 1] = hb[t].y;
                ha[4 * t + 2] = hb[t].z; ha[4 * t + 3] = hb[t].w;
            }
#pragma unroll 8
            for (int d = 0; d < NDIM; ++d) {
                float x = Xs[hm * 36 + d];
#pragma unroll
                for (int t = 0; t < 4; ++t) {
                    float4 w = *(const float4*)&w1s[d * NHID + 32 * t + 4 * jbi];
                    ha[4 * t] += x * w.x; ha[4 * t + 1] += x * w.y;
                    ha[4 * t + 2] += x * w.z; ha[4 * t + 3] += x * w.w;
                }
            }
#pragma unroll
            for (int t = 0; t < 4; ++t) {
                int jb = 32 * t + 4 * jbi;
                hs[hm * 133 + jb] = gelu_fast(ha[4 * t]);
                hs[hm * 133 + jb + 1] = gelu_fast(ha[4 * t + 1]);
                hs[hm * 133 + jb + 2] = gelu_fast(ha[4 * t + 2]);
                hs[hm * 133 + jb + 3] = gelu_fast(ha[4 * t + 3]);
            }
        }
        __syncthreads();
        {   // V tile
            int r = tid & 31, d0 = (tid >> 5) * 4;
            float4 a = *(const float4*)&Zs[128 * 36 + d0];
#pragma unroll 8
            for (int k = 0; k < NHID; ++k) {
                float h = hs[r * 133 + k];
                float4 z = *(const float4*)&Zs[k * 36 + d0];
                a.x += h * z.x; a.y += h * z.y; a.z += h * z.z; a.w += h * z.w;
            }
            vs[r * 33 + d0] = a.x; vs[r * 33 + d0 + 1] = a.y;
            vs[r * 33 + d0 + 2] = a.z; vs[r * 33 + d0 + 3] = a.w;
        }
        __syncthreads();
        {   // Wf projection
#pragma unroll
            for (int i = 0; i < 4; ++i) {
                int q = tid + i * 256;
                int r = q >> 5, d = q & 31;
                float v = vs[r * 33 + d];
                const float* wr = Wf + ((size_t)(n0 + r) * NDIM + d) * NCLASS;
#pragma unroll
                for (int c = 0; c < NCLASS; ++c) acc[c] += v * wr[c];
            }
        }
    }

#pragma unroll
    for (int off = 32; off >= 1; off >>= 1)
#pragma unroll
        for (int c = 0; c < NCLASS; ++c) acc[c] += __shfl_down(acc[c], off);
    if ((tid & 63) == 0) {
#pragma unroll
        for (int c = 0; c < NCLASS; ++c) red[tid >> 6][c] = acc[c];
    }
    __syncthreads();
    if (tid < NCLASS)
        atomicAdd(&out[b * NCLASS + tid],
                  red[0][tid] + red[1][tid] + red[2][tid] + red[3][tid]);
}

// ---------------------------------------------------------------------------
extern "C" void kernel_launch(void* const* d_in, const int* in_sizes, int n_in,
                              void* d_out, int out_size, void* d_ws, size_t ws_size,
                              hipStream_t stream) {
    const int*   data = (const int*)d_in[0];
    const float* emb  = (const float*)d_in[1];
    const float* fw1  = (const float*)d_in[2];
    const float* fb1  = (const float*)d_in[3];
    const float* fw2  = (const float*)d_in[4];
    const float* fb2  = (const float*)d_in[5];
    const float* Wf   = (const float*)d_in[6];
    const float* bf   = (const float*)d_in[7];
    float* out = (float*)d_out;

    float* X      = (float*)d_ws;                         // 1,048,576 f
    float* CTpart = X + NB * NVEC * NDIM;                 // 8*64*17424 f (35.7 MB)
    float* CT     = CTpart + (size_t)MSC * NW * NB * CTSLOT;
    float* Zbuf   = CT + (size_t)NW * NB * CTSLOT;

    k_embed<<<dim3((NB * NVEC * NDIM) / 256), 256, 0, stream>>>(data, emb, bf, X, out);
    k_C<<<dim3(MSC, NB, NW), 256, 0, stream>>>(X, fw1, fb1, fw2, fb2, CTpart);
    k_Cred<<<dim3(4257), 256, 0, stream>>>(CTpart, CT);
    k_Z<<<dim3(4, NB), 192, 0, stream>>>(CT, Zbuf);
    k_out<<<dim3(16, NB), 256, 0, stream>>>(X, fw1, fb1, Zbuf, Wf, out);
}